// Round 4
// baseline (861.135 us; speedup 1.0000x reference)
//
#include <hip/hip_runtime.h>

#define Nn 32
#define Cc 64
#define Vv 25
#define Tt 1024

typedef __attribute__((ext_vector_type(4))) float f32x4;
typedef __attribute__((ext_vector_type(8))) short bf16x8;
typedef __attribute__((ext_vector_type(4))) unsigned short u16x4;

__device__ __forceinline__ unsigned short f2bf(float f) {
    union { float f; unsigned u; } a; a.f = f;
    unsigned u = a.u;
    u += 0x7fff + ((u >> 16) & 1);   // RNE
    return (unsigned short)(u >> 16);
}

__device__ __forceinline__ void gl_lds16(const unsigned short* g, unsigned short* l) {
    __builtin_amdgcn_global_load_lds(
        (const __attribute__((address_space(1))) unsigned int*)g,
        (__attribute__((address_space(3))) unsigned int*)l, 16, 0, 0);
}

// ---------------- fast path ----------------

// Fused prep: blocks [0,625) build Weff (swizzled); blocks [625,3825) convert
// x -> xb (bf16, swizzled layout), 64c' x 256t tile per block.
// Weff[v][w] tile (64c x 64c') bf16, XOR-swizzled: within a 128B row c,
// logical 16B chunk jl stored at physical chunk jl^(c&7).
// xb[n][w][t][c'] with identical per-t-row swizzle: chunk jl at jl^(t&7).
// x-convert is LDS-FREE: each thread owns a full c'-octet (8 rows) for 4 t's,
// packs the final 16B chunk in registers, stores straight to xb. (R3's LDS
// transpose was a ~16-way bank conflict on ds_write_b16: lanes differing only
// in tc hit addresses 1024B apart = same bank.)
__global__ __launch_bounds__(256) void prep_fused(
        const float* __restrict__ x, const float* __restrict__ W,
        const float* __restrict__ A, unsigned short* __restrict__ xb,
        unsigned short* __restrict__ Weff) {
    int bid = blockIdx.x;
    if (bid < Vv * Vv) {
        // ---- Weff part ----
        int v = bid / Vv;
        int w = bid - v * Vv;
        float a0 = A[(0 * Vv + w) * Vv + v];
        float a1 = A[(1 * Vv + w) * Vv + v];
        float a2 = A[(2 * Vv + w) * Vv + v];
        const float* Wb = W + (size_t)w * 192 * 64;
        unsigned short* o = Weff + (size_t)(v * Vv + w) * 4096;
        int c  = threadIdx.x >> 2;
        int c0 = (threadIdx.x & 3) * 16;
        #pragma unroll
        for (int i = 0; i < 16; ++i) {
            int cp = c0 + i;
            float val = a0 * Wb[(c * 3 + 0) * 64 + cp]
                      + a1 * Wb[(c * 3 + 1) * 64 + cp]
                      + a2 * Wb[(c * 3 + 2) * 64 + cp];
            int jl = cp >> 3;
            o[c * 64 + ((jl ^ (c & 7)) << 3) + (cp & 7)] = f2bf(val);
        }
        return;
    }
    // ---- x-convert part: tile = (n, w, 256t), no LDS ----
    int pid = bid - Vv * Vv;
    int n = pid / (Vv * 4);
    int rem = pid - n * (Vv * 4);
    int w = rem >> 2;
    int t0 = (rem & 3) << 8;

    int tid = threadIdx.x;
    int wv = tid >> 6;            // t-subwindow: [wv*64, wv*64+64)
    int l  = tid & 63;
    int tc = l & 15;              // 4-t group within subwindow
    int jh = l >> 4;              // octet-pair 0..3

    const float* xn = x + ((size_t)n * Cc * Vv + w) * Tt + t0 + wv * 64 + tc * 4;
    unsigned short* dst = xb + ((size_t)(n * Vv + w) * Tt + t0) * 64;

    #pragma unroll
    for (int it = 0; it < 2; ++it) {
        int jl = jh * 2 + it;     // c'-octet 0..7
        f32x4 f[8];
        #pragma unroll
        for (int k = 0; k < 8; ++k) {
            int r = jl * 8 + k;
            f[k] = __builtin_nontemporal_load(
                (const f32x4*)(xn + (size_t)r * (Vv * Tt)));
        }
        #pragma unroll
        for (int j = 0; j < 4; ++j) {
            bf16x8 o;
            #pragma unroll
            for (int k = 0; k < 8; ++k) o[k] = (short)f2bf(f[k][j]);
            int tl = wv * 64 + tc * 4 + j;
            int pc = jl ^ (tl & 7);
            *(bf16x8*)&dst[tl * 64 + pc * 8] = o;   // 16B, lands in L2 for gc
        }
    }
}

// out[n, 0:64, v, t0:t0+256] = sum_w Weff[v,w] @ xb[n,w,t0:t0+256,:]
// Distance-2 pipeline: A staged via global_load_lds into RING-4 LDS (safe:
// buffer rewritten at issue(w) was last read at COMPUTE(w-2), before
// barrier(w-1) which all waves passed). B direct-to-reg, 3 buffers.
// Uniform counted s_waitcnt vmcnt(20) = ops issued in the 2 younger steps
// (2 DMA + 8 B-loads each). Out-stores nontemporal (write-once; keep xb in L2).
// 3 blocks/CU (VGPR 108 <= 168 cap, LDS 96KB): 3 waves/SIMD stretches the
// wall time under the D=2 lookahead to ~930cy, covering HBM-miss latency.
__global__ __launch_bounds__(256, 3) void gc_fast(
        const unsigned short* __restrict__ xb,
        const unsigned short* __restrict__ Weff,
        float* __restrict__ out) {
    __shared__ __align__(16) unsigned short wa[4][4096];

    int bid = blockIdx.x;                 // 3200 = 8 xcd * (16 slices * 25 v), v fastest
    int xcd = bid & 7;
    int lid = bid >> 3;
    int v = lid % Vv;
    int s = lid / Vv;                     // 0..15
    int slice = (xcd << 4) + s;           // 0..127
    int n  = slice >> 2;
    int t0 = (slice & 3) << 8;

    int tid = threadIdx.x;
    int lane = tid & 63, wv = tid >> 6;
    int m = lane & 15, quad = lane >> 4;

    const unsigned short* wg = Weff + (size_t)v * (Vv * 4096);
    const unsigned short* xbase = xb + ((size_t)(n * Vv) * Tt + t0) * 64;

    int coff0 = ((quad)     ^ (m & 7)) << 3;   // kc=0 chunk offset (swizzled)
    int coff1 = ((4 + quad) ^ (m & 7)) << 3;   // kc=1
    int trow[4], arow[4];
    #pragma unroll
    for (int ni = 0; ni < 4; ++ni) trow[ni] = (wv * 64 + ni * 16 + m) * 64;
    #pragma unroll
    for (int mi = 0; mi < 4; ++mi) arow[mi] = (mi * 16 + m) * 64;

    f32x4 acc[4][4];
    #pragma unroll
    for (int i = 0; i < 4; ++i)
        #pragma unroll
        for (int j = 0; j < 4; ++j)
            acc[i][j] = (f32x4){0.f, 0.f, 0.f, 0.f};

    bf16x8 b0[8], b1[8], b2[8];

#define ISSUE_A(WBUF, w_) do { \
    const unsigned short* s_ = wg + (size_t)(w_) * 4096 + tid * 8; \
    gl_lds16(s_,        &wa[WBUF][tid * 8]); \
    gl_lds16(s_ + 2048, &wa[WBUF][2048 + tid * 8]); \
} while (0)

#define ISSUE_B(BN, w_) do { \
    const unsigned short* xw_ = xbase + (size_t)(w_) * (Tt * 64); \
    _Pragma("unroll") \
    for (int ni_ = 0; ni_ < 4; ++ni_) { \
        BN[ni_]     = *(const bf16x8*)(xw_ + trow[ni_] + coff0); \
        BN[ni_ + 4] = *(const bf16x8*)(xw_ + trow[ni_] + coff1); \
    } \
} while (0)

#define COMPUTE(RBUF, BC) do { \
    const unsigned short* cur_ = &wa[RBUF][0]; \
    bf16x8 af_[8]; \
    _Pragma("unroll") \
    for (int mi_ = 0; mi_ < 4; ++mi_) { \
        af_[mi_]     = *(const bf16x8*)(cur_ + arow[mi_] + coff0); \
        af_[mi_ + 4] = *(const bf16x8*)(cur_ + arow[mi_] + coff1); \
    } \
    __builtin_amdgcn_s_setprio(1); \
    _Pragma("unroll") \
    for (int mi_ = 0; mi_ < 4; ++mi_) \
        _Pragma("unroll") \
        for (int ni_ = 0; ni_ < 4; ++ni_) \
            acc[mi_][ni_] = __builtin_amdgcn_mfma_f32_16x16x32_bf16( \
                af_[mi_], BC[ni_], acc[mi_][ni_], 0, 0, 0); \
    _Pragma("unroll") \
    for (int mi_ = 0; mi_ < 4; ++mi_) \
        _Pragma("unroll") \
        for (int ni_ = 0; ni_ < 4; ++ni_) \
            acc[mi_][ni_] = __builtin_amdgcn_mfma_f32_16x16x32_bf16( \
                af_[mi_ + 4], BC[ni_ + 4], acc[mi_][ni_], 0, 0, 0); \
    __builtin_amdgcn_s_setprio(0); \
} while (0)

#define STEP(RB, WB, BC, BN, w_) do { \
    ISSUE_A(WB, (w_) + 2); \
    ISSUE_B(BN, (w_) + 2); \
    __builtin_amdgcn_sched_barrier(0); \
    asm volatile("s_waitcnt vmcnt(20)" ::: "memory"); \
    __builtin_amdgcn_sched_barrier(0); \
    __builtin_amdgcn_s_barrier(); \
    __builtin_amdgcn_sched_barrier(0); \
    COMPUTE(RB, BC); \
} while (0)

    // prologue: (A0,B0), (A1,B1) -- virtual steps -2,-1
    ISSUE_A(0, 0);
    ISSUE_B(b0, 0);
    ISSUE_A(1, 1);
    ISSUE_B(b1, 1);
    __builtin_amdgcn_sched_barrier(0);

    // w = 0..22 : RB=w%4, WB=(w+2)%4, BC=b{w%3}, BN=b{(w+2)%3}
    STEP(0, 2, b0, b2,  0);
    STEP(1, 3, b1, b0,  1);
    STEP(2, 0, b2, b1,  2);
    STEP(3, 1, b0, b2,  3);
    STEP(0, 2, b1, b0,  4);
    STEP(1, 3, b2, b1,  5);
    STEP(2, 0, b0, b2,  6);
    STEP(3, 1, b1, b0,  7);
    STEP(0, 2, b2, b1,  8);
    STEP(1, 3, b0, b2,  9);
    STEP(2, 0, b1, b0, 10);
    STEP(3, 1, b2, b1, 11);
    STEP(0, 2, b0, b2, 12);
    STEP(1, 3, b1, b0, 13);
    STEP(2, 0, b2, b1, 14);
    STEP(3, 1, b0, b2, 15);
    STEP(0, 2, b1, b0, 16);
    STEP(1, 3, b2, b1, 17);
    STEP(2, 0, b0, b2, 18);
    STEP(3, 1, b1, b0, 19);
    STEP(0, 2, b2, b1, 20);
    STEP(1, 3, b0, b2, 21);
    STEP(2, 0, b1, b0, 22);
    // tail w=23: only (A24,B24) in flight -> vmcnt(10)
    asm volatile("s_waitcnt vmcnt(10)" ::: "memory");
    __builtin_amdgcn_sched_barrier(0);
    __builtin_amdgcn_s_barrier();
    __builtin_amdgcn_sched_barrier(0);
    COMPUTE(3, b2);
    // tail w=24
    asm volatile("s_waitcnt vmcnt(0)" ::: "memory");
    __builtin_amdgcn_sched_barrier(0);
    __builtin_amdgcn_s_barrier();
    __builtin_amdgcn_sched_barrier(0);
    COMPUTE(0, b0);

#undef ISSUE_A
#undef ISSUE_B
#undef COMPUTE
#undef STEP

    // epilogue: D layout col(t)=lane&15, row(c)=quad*4+reg  (verified in R1)
    // nontemporal: out is write-once, keep xb resident in L2.
    float* og = out + ((size_t)n * Cc * Vv + v) * Tt + t0 + wv * 64 + m;
    #pragma unroll
    for (int mi = 0; mi < 4; ++mi)
        #pragma unroll
        for (int r = 0; r < 4; ++r) {
            int c = mi * 16 + quad * 4 + r;
            float* orow = og + (size_t)c * Vv * Tt;
            #pragma unroll
            for (int ni = 0; ni < 4; ++ni)
                __builtin_nontemporal_store(acc[mi][ni][r], &orow[ni * 16]);
        }
}

// ---------------- fallback path (R1, proven) ----------------

__global__ __launch_bounds__(256) void weff_prep_plain(
        const float* __restrict__ W, const float* __restrict__ A,
        unsigned short* __restrict__ Weff) {
    int v = blockIdx.x / Vv;
    int w = blockIdx.x - v * Vv;
    float a0 = A[(0 * Vv + w) * Vv + v];
    float a1 = A[(1 * Vv + w) * Vv + v];
    float a2 = A[(2 * Vv + w) * Vv + v];
    const float* Wb = W + (size_t)w * 192 * 64;
    unsigned short* o = Weff + (size_t)(v * Vv + w) * 4096;
    int e0 = threadIdx.x * 16;
    #pragma unroll
    for (int i = 0; i < 16; ++i) {
        int e = e0 + i;
        int c = e >> 6, cp = e & 63;
        float val = a0 * Wb[(c * 3 + 0) * 64 + cp]
                  + a1 * Wb[(c * 3 + 1) * 64 + cp]
                  + a2 * Wb[(c * 3 + 2) * 64 + cp];
        o[e] = f2bf(val);
    }
}

__global__ __launch_bounds__(256, 2) void gc_plain(
        const float* __restrict__ x, const unsigned short* __restrict__ Weff,
        float* __restrict__ out) {
    __shared__ __align__(16) unsigned short xs[256 * 72];
    __shared__ __align__(16) unsigned short wa[64 * 72];
    int bid = blockIdx.x;
    int xcd = bid & 7;
    int lid = bid >> 3;
    int v, s;
    if (lid < 13 * 16) { v = lid % 13;            s = lid / 13; }
    else { int l2 = lid - 13 * 16; v = 13 + l2 % 12; s = l2 / 12; }
    int slice = (xcd << 4) + s;
    int n  = slice >> 2;
    int t0 = (slice & 3) << 8;
    int tid  = threadIdx.x;
    int lane = tid & 63;
    int wv   = tid >> 6;
    int m    = lane & 15;
    int quad = lane >> 4;
    int cc = tid & 7;
    int tt = tid >> 3;
    f32x4 acc[4][4];
    #pragma unroll
    for (int i = 0; i < 4; ++i)
        #pragma unroll
        for (int j = 0; j < 4; ++j)
            acc[i][j] = (f32x4){0.f, 0.f, 0.f, 0.f};
    const float* xg = x + (size_t)n * Cc * Vv * Tt + t0 + tt * 4;
    const bf16x8* wg = (const bf16x8*)(Weff + (size_t)v * Vv * 4096);
    for (int w = 0; w < Vv; ++w) {
        if (w) __syncthreads();
        #pragma unroll
        for (int r = 0; r < 2; ++r) {
            int q = r * 256 + tid;
            int c = q >> 3, b = q & 7;
            *(bf16x8*)&wa[c * 72 + b * 8] = wg[w * 512 + q];
        }
        {
            bf16x8 rows[8];
            #pragma unroll
            for (int i = 0; i < 8; ++i) {
                int cp = cc * 8 + i;
                const float* p = xg + ((size_t)cp * Vv + w) * Tt;
                float4 f0 = *(const float4*)p;
                float4 f1 = *(const float4*)(p + 128);
                rows[0][i] = (short)f2bf(f0.x); rows[1][i] = (short)f2bf(f0.y);
                rows[2][i] = (short)f2bf(f0.z); rows[3][i] = (short)f2bf(f0.w);
                rows[4][i] = (short)f2bf(f1.x); rows[5][i] = (short)f2bf(f1.y);
                rows[6][i] = (short)f2bf(f1.z); rows[7][i] = (short)f2bf(f1.w);
            }
            #pragma unroll
            for (int j = 0; j < 4; ++j) {
                *(bf16x8*)&xs[(tt * 4 + j) * 72 + cc * 8]       = rows[j];
                *(bf16x8*)&xs[(128 + tt * 4 + j) * 72 + cc * 8] = rows[4 + j];
            }
        }
        __syncthreads();
        #pragma unroll
        for (int kc = 0; kc < 2; ++kc) {
            int ko = kc * 32 + quad * 8;
            bf16x8 afr[4], bfr[4];
            #pragma unroll
            for (int mi = 0; mi < 4; ++mi)
                afr[mi] = *(const bf16x8*)&wa[(mi * 16 + m) * 72 + ko];
            #pragma unroll
            for (int ni = 0; ni < 4; ++ni)
                bfr[ni] = *(const bf16x8*)&xs[(wv * 64 + ni * 16 + m) * 72 + ko];
            #pragma unroll
            for (int mi = 0; mi < 4; ++mi)
                #pragma unroll
                for (int ni = 0; ni < 4; ++ni)
                    acc[mi][ni] = __builtin_amdgcn_mfma_f32_16x16x32_bf16(
                        afr[mi], bfr[ni], acc[mi][ni], 0, 0, 0);
        }
    }
    float* og = out + ((size_t)n * Cc * Vv + v) * Tt + t0 + wv * 64 + m;
    #pragma unroll
    for (int mi = 0; mi < 4; ++mi)
        #pragma unroll
        for (int r = 0; r < 4; ++r) {
            int c = mi * 16 + quad * 4 + r;
            float* orow = og + (size_t)c * Vv * Tt;
            #pragma unroll
            for (int ni = 0; ni < 4; ++ni)
                orow[ni * 16] = acc[mi][ni][r];
        }
}

extern "C" void kernel_launch(void* const* d_in, const int* in_sizes, int n_in,
                              void* d_out, int out_size, void* d_ws, size_t ws_size,
                              hipStream_t stream) {
    const float* x = (const float*)d_in[0];   // [32,64,25,1024]
    const float* W = (const float*)d_in[1];   // [25,192,64]
    const float* A = (const float*)d_in[2];   // [3,25,25]
    float* out = (float*)d_out;

    const size_t xb_elems   = (size_t)Nn * Vv * Tt * 64;       // 52,428,800
    const size_t weff_elems = (size_t)Vv * Vv * 4096;          //  2,560,000
    const size_t need = (xb_elems + weff_elems) * sizeof(unsigned short);

    if (ws_size >= need) {
        unsigned short* xb   = (unsigned short*)d_ws;
        unsigned short* Weff = xb + xb_elems;
        prep_fused<<<dim3(Vv * Vv + Nn * Vv * 4), dim3(256), 0, stream>>>(x, W, A, xb, Weff);
        gc_fast<<<dim3(3200), dim3(256), 0, stream>>>(xb, Weff, out);
    } else {
        unsigned short* Weff = (unsigned short*)d_ws;
        weff_prep_plain<<<dim3(Vv * Vv), dim3(256), 0, stream>>>(W, A, Weff);
        gc_plain<<<dim3(3200), dim3(256), 0, stream>>>(x, Weff, out);
    }
}

// Round 5
// 500.645 us; speedup vs baseline: 1.7201x; 1.7201x over previous
//
#include <hip/hip_runtime.h>

#define Nn 32
#define Cc 64
#define Vv 25
#define Tt 1024

typedef __attribute__((ext_vector_type(4))) float f32x4;
typedef __attribute__((ext_vector_type(8))) short bf16x8;
typedef __attribute__((ext_vector_type(4))) unsigned short u16x4;

__device__ __forceinline__ unsigned short f2bf(float f) {
    union { float f; unsigned u; } a; a.f = f;
    unsigned u = a.u;
    u += 0x7fff + ((u >> 16) & 1);   // RNE
    return (unsigned short)(u >> 16);
}

__device__ __forceinline__ void gl_lds16(const unsigned short* g, unsigned short* l) {
    __builtin_amdgcn_global_load_lds(
        (const __attribute__((address_space(1))) unsigned int*)g,
        (__attribute__((address_space(3))) unsigned int*)l, 16, 0, 0);
}

// ---------------- fast path ----------------

// Fused prep: blocks [0,625) build Weff (swizzled); blocks [625,7025) convert
// x -> xb (bf16, swizzled), 64c' x 128t tile per block, LDS-FREE with BOTH
// sides 128B-coalesced:
//   lane = (jl = c'-octet 0..7, tg = t-quad 0..7); per load instr the 8 tg
//   lanes of one jl read 128B contiguous of one x row (8 rows/instr); per
//   store instr the 8 jl lanes cover all 8 swizzled chunks of one 128B xb
//   row (XOR is a permutation within the row), 8 rows/instr.
// Weff[v][w] tile (64c x 64c') bf16, XOR-swizzled: within a 128B row c,
// logical 16B chunk jl stored at physical chunk jl^(c&7).
// xb[n][w][t][c'] with identical per-t-row swizzle: chunk jl at jl^(t&7).
__global__ __launch_bounds__(256) void prep_fused(
        const float* __restrict__ x, const float* __restrict__ W,
        const float* __restrict__ A, unsigned short* __restrict__ xb,
        unsigned short* __restrict__ Weff) {
    int bid = blockIdx.x;
    if (bid < Vv * Vv) {
        // ---- Weff part ----
        int v = bid / Vv;
        int w = bid - v * Vv;
        float a0 = A[(0 * Vv + w) * Vv + v];
        float a1 = A[(1 * Vv + w) * Vv + v];
        float a2 = A[(2 * Vv + w) * Vv + v];
        const float* Wb = W + (size_t)w * 192 * 64;
        unsigned short* o = Weff + (size_t)(v * Vv + w) * 4096;
        int c  = threadIdx.x >> 2;
        int c0 = (threadIdx.x & 3) * 16;
        #pragma unroll
        for (int i = 0; i < 16; ++i) {
            int cp = c0 + i;
            float val = a0 * Wb[(c * 3 + 0) * 64 + cp]
                      + a1 * Wb[(c * 3 + 1) * 64 + cp]
                      + a2 * Wb[(c * 3 + 2) * 64 + cp];
            int jl = cp >> 3;
            o[c * 64 + ((jl ^ (c & 7)) << 3) + (cp & 7)] = f2bf(val);
        }
        return;
    }
    // ---- x-convert part: tile = (n, w, 128t), no LDS ----
    int pid = bid - Vv * Vv;
    int n = pid / (Vv * 8);
    int rem = pid - n * (Vv * 8);
    int w = rem >> 3;
    int t0 = (rem & 7) << 7;      // 128-t slice

    int tid = threadIdx.x;
    int wv = tid >> 6;            // wave covers t-window [t0+wv*32, +32)
    int l  = tid & 63;
    int jl = l & 7;               // c'-octet 0..7
    int tg = l >> 3;              // t-quad 0..7

    int tbase = t0 + wv * 32 + tg * 4;
    const float* xn = x + ((size_t)(n * Cc) * Vv + w) * Tt + tbase;
    unsigned short* dst = xb + ((size_t)(n * Vv + w) * Tt) * 64;

    f32x4 f[8];
    #pragma unroll
    for (int k = 0; k < 8; ++k) {
        int r = jl * 8 + k;
        f[k] = __builtin_nontemporal_load(
            (const f32x4*)(xn + (size_t)r * (Vv * Tt)));
    }
    #pragma unroll
    for (int j = 0; j < 4; ++j) {
        bf16x8 o;
        #pragma unroll
        for (int k = 0; k < 8; ++k) o[k] = (short)f2bf(f[k][j]);
        int tl = tbase + j;
        int pc = jl ^ (tl & 7);
        *(bf16x8*)&dst[(size_t)tl * 64 + pc * 8] = o;   // 128B/row per wave
    }
}

// out[n, 0:64, v, t0:t0+256] = sum_w Weff[v,w] @ xb[n,w,t0:t0+256,:]
// Distance-2 pipeline: A staged via global_load_lds into RING-4 LDS (safe:
// buffer rewritten at issue(w) was last read at COMPUTE(w-2), before
// barrier(w-1) which all waves passed). B direct-to-reg, 3 buffers.
// Uniform counted s_waitcnt vmcnt(20) = ops issued in the 2 younger steps
// (2 DMA + 8 B-loads each). Out-stores nontemporal (write-once; keep xb in L2).
// NOTE (R4 post-mortem): real register need is ~108 arch VGPR + 64 AGPR
// (unified file ~172) -> 2 waves/SIMD is the hard occupancy point. Any
// launch_bounds above (256,2) forces scratch spill (WRITE_SIZE 205MB->1.5GB).
__global__ __launch_bounds__(256, 2) void gc_fast(
        const unsigned short* __restrict__ xb,
        const unsigned short* __restrict__ Weff,
        float* __restrict__ out) {
    __shared__ __align__(16) unsigned short wa[4][4096];

    int bid = blockIdx.x;                 // 3200 = 8 xcd * (16 slices * 25 v), v fastest
    int xcd = bid & 7;
    int lid = bid >> 3;
    int v = lid % Vv;
    int s = lid / Vv;                     // 0..15
    int slice = (xcd << 4) + s;           // 0..127
    int n  = slice >> 2;
    int t0 = (slice & 3) << 8;

    int tid = threadIdx.x;
    int lane = tid & 63, wv = tid >> 6;
    int m = lane & 15, quad = lane >> 4;

    const unsigned short* wg = Weff + (size_t)v * (Vv * 4096);
    const unsigned short* xbase = xb + ((size_t)(n * Vv) * Tt + t0) * 64;

    int coff0 = ((quad)     ^ (m & 7)) << 3;   // kc=0 chunk offset (swizzled)
    int coff1 = ((4 + quad) ^ (m & 7)) << 3;   // kc=1
    int trow[4], arow[4];
    #pragma unroll
    for (int ni = 0; ni < 4; ++ni) trow[ni] = (wv * 64 + ni * 16 + m) * 64;
    #pragma unroll
    for (int mi = 0; mi < 4; ++mi) arow[mi] = (mi * 16 + m) * 64;

    f32x4 acc[4][4];
    #pragma unroll
    for (int i = 0; i < 4; ++i)
        #pragma unroll
        for (int j = 0; j < 4; ++j)
            acc[i][j] = (f32x4){0.f, 0.f, 0.f, 0.f};

    bf16x8 b0[8], b1[8], b2[8];

#define ISSUE_A(WBUF, w_) do { \
    const unsigned short* s_ = wg + (size_t)(w_) * 4096 + tid * 8; \
    gl_lds16(s_,        &wa[WBUF][tid * 8]); \
    gl_lds16(s_ + 2048, &wa[WBUF][2048 + tid * 8]); \
} while (0)

#define ISSUE_B(BN, w_) do { \
    const unsigned short* xw_ = xbase + (size_t)(w_) * (Tt * 64); \
    _Pragma("unroll") \
    for (int ni_ = 0; ni_ < 4; ++ni_) { \
        BN[ni_]     = *(const bf16x8*)(xw_ + trow[ni_] + coff0); \
        BN[ni_ + 4] = *(const bf16x8*)(xw_ + trow[ni_] + coff1); \
    } \
} while (0)

#define COMPUTE(RBUF, BC) do { \
    const unsigned short* cur_ = &wa[RBUF][0]; \
    bf16x8 af_[8]; \
    _Pragma("unroll") \
    for (int mi_ = 0; mi_ < 4; ++mi_) { \
        af_[mi_]     = *(const bf16x8*)(cur_ + arow[mi_] + coff0); \
        af_[mi_ + 4] = *(const bf16x8*)(cur_ + arow[mi_] + coff1); \
    } \
    __builtin_amdgcn_s_setprio(1); \
    _Pragma("unroll") \
    for (int mi_ = 0; mi_ < 4; ++mi_) \
        _Pragma("unroll") \
        for (int ni_ = 0; ni_ < 4; ++ni_) \
            acc[mi_][ni_] = __builtin_amdgcn_mfma_f32_16x16x32_bf16( \
                af_[mi_], BC[ni_], acc[mi_][ni_], 0, 0, 0); \
    _Pragma("unroll") \
    for (int mi_ = 0; mi_ < 4; ++mi_) \
        _Pragma("unroll") \
        for (int ni_ = 0; ni_ < 4; ++ni_) \
            acc[mi_][ni_] = __builtin_amdgcn_mfma_f32_16x16x32_bf16( \
                af_[mi_ + 4], BC[ni_ + 4], acc[mi_][ni_], 0, 0, 0); \
    __builtin_amdgcn_s_setprio(0); \
} while (0)

#define STEP(RB, WB, BC, BN, w_) do { \
    ISSUE_A(WB, (w_) + 2); \
    ISSUE_B(BN, (w_) + 2); \
    __builtin_amdgcn_sched_barrier(0); \
    asm volatile("s_waitcnt vmcnt(20)" ::: "memory"); \
    __builtin_amdgcn_sched_barrier(0); \
    __builtin_amdgcn_s_barrier(); \
    __builtin_amdgcn_sched_barrier(0); \
    COMPUTE(RB, BC); \
} while (0)

    // prologue: (A0,B0), (A1,B1) -- virtual steps -2,-1
    ISSUE_A(0, 0);
    ISSUE_B(b0, 0);
    ISSUE_A(1, 1);
    ISSUE_B(b1, 1);
    __builtin_amdgcn_sched_barrier(0);

    // w = 0..22 : RB=w%4, WB=(w+2)%4, BC=b{w%3}, BN=b{(w+2)%3}
    STEP(0, 2, b0, b2,  0);
    STEP(1, 3, b1, b0,  1);
    STEP(2, 0, b2, b1,  2);
    STEP(3, 1, b0, b2,  3);
    STEP(0, 2, b1, b0,  4);
    STEP(1, 3, b2, b1,  5);
    STEP(2, 0, b0, b2,  6);
    STEP(3, 1, b1, b0,  7);
    STEP(0, 2, b2, b1,  8);
    STEP(1, 3, b0, b2,  9);
    STEP(2, 0, b1, b0, 10);
    STEP(3, 1, b2, b1, 11);
    STEP(0, 2, b0, b2, 12);
    STEP(1, 3, b1, b0, 13);
    STEP(2, 0, b2, b1, 14);
    STEP(3, 1, b0, b2, 15);
    STEP(0, 2, b1, b0, 16);
    STEP(1, 3, b2, b1, 17);
    STEP(2, 0, b0, b2, 18);
    STEP(3, 1, b1, b0, 19);
    STEP(0, 2, b2, b1, 20);
    STEP(1, 3, b0, b2, 21);
    STEP(2, 0, b1, b0, 22);
    // tail w=23: only (A24,B24) in flight -> vmcnt(10)
    asm volatile("s_waitcnt vmcnt(10)" ::: "memory");
    __builtin_amdgcn_sched_barrier(0);
    __builtin_amdgcn_s_barrier();
    __builtin_amdgcn_sched_barrier(0);
    COMPUTE(3, b2);
    // tail w=24
    asm volatile("s_waitcnt vmcnt(0)" ::: "memory");
    __builtin_amdgcn_sched_barrier(0);
    __builtin_amdgcn_s_barrier();
    __builtin_amdgcn_sched_barrier(0);
    COMPUTE(0, b0);

#undef ISSUE_A
#undef ISSUE_B
#undef COMPUTE
#undef STEP

    // epilogue: D layout col(t)=lane&15, row(c)=quad*4+reg  (verified in R1)
    // nontemporal: out is write-once, keep xb resident in L2.
    float* og = out + ((size_t)n * Cc * Vv + v) * Tt + t0 + wv * 64 + m;
    #pragma unroll
    for (int mi = 0; mi < 4; ++mi)
        #pragma unroll
        for (int r = 0; r < 4; ++r) {
            int c = mi * 16 + quad * 4 + r;
            float* orow = og + (size_t)c * Vv * Tt;
            #pragma unroll
            for (int ni = 0; ni < 4; ++ni)
                __builtin_nontemporal_store(acc[mi][ni][r], &orow[ni * 16]);
        }
}

// ---------------- fallback path (R1, proven) ----------------

__global__ __launch_bounds__(256) void weff_prep_plain(
        const float* __restrict__ W, const float* __restrict__ A,
        unsigned short* __restrict__ Weff) {
    int v = blockIdx.x / Vv;
    int w = blockIdx.x - v * Vv;
    float a0 = A[(0 * Vv + w) * Vv + v];
    float a1 = A[(1 * Vv + w) * Vv + v];
    float a2 = A[(2 * Vv + w) * Vv + v];
    const float* Wb = W + (size_t)w * 192 * 64;
    unsigned short* o = Weff + (size_t)(v * Vv + w) * 4096;
    int e0 = threadIdx.x * 16;
    #pragma unroll
    for (int i = 0; i < 16; ++i) {
        int e = e0 + i;
        int c = e >> 6, cp = e & 63;
        float val = a0 * Wb[(c * 3 + 0) * 64 + cp]
                  + a1 * Wb[(c * 3 + 1) * 64 + cp]
                  + a2 * Wb[(c * 3 + 2) * 64 + cp];
        o[e] = f2bf(val);
    }
}

__global__ __launch_bounds__(256, 2) void gc_plain(
        const float* __restrict__ x, const unsigned short* __restrict__ Weff,
        float* __restrict__ out) {
    __shared__ __align__(16) unsigned short xs[256 * 72];
    __shared__ __align__(16) unsigned short wa[64 * 72];
    int bid = blockIdx.x;
    int xcd = bid & 7;
    int lid = bid >> 3;
    int v, s;
    if (lid < 13 * 16) { v = lid % 13;            s = lid / 13; }
    else { int l2 = lid - 13 * 16; v = 13 + l2 % 12; s = l2 / 12; }
    int slice = (xcd << 4) + s;
    int n  = slice >> 2;
    int t0 = (slice & 3) << 8;
    int tid  = threadIdx.x;
    int lane = tid & 63;
    int wv   = tid >> 6;
    int m    = lane & 15;
    int quad = lane >> 4;
    int cc = tid & 7;
    int tt = tid >> 3;
    f32x4 acc[4][4];
    #pragma unroll
    for (int i = 0; i < 4; ++i)
        #pragma unroll
        for (int j = 0; j < 4; ++j)
            acc[i][j] = (f32x4){0.f, 0.f, 0.f, 0.f};
    const float* xg = x + (size_t)n * Cc * Vv * Tt + t0 + tt * 4;
    const bf16x8* wg = (const bf16x8*)(Weff + (size_t)v * Vv * 4096);
    for (int w = 0; w < Vv; ++w) {
        if (w) __syncthreads();
        #pragma unroll
        for (int r = 0; r < 2; ++r) {
            int q = r * 256 + tid;
            int c = q >> 3, b = q & 7;
            *(bf16x8*)&wa[c * 72 + b * 8] = wg[w * 512 + q];
        }
        {
            bf16x8 rows[8];
            #pragma unroll
            for (int i = 0; i < 8; ++i) {
                int cp = cc * 8 + i;
                const float* p = xg + ((size_t)cp * Vv + w) * Tt;
                float4 f0 = *(const float4*)p;
                float4 f1 = *(const float4*)(p + 128);
                rows[0][i] = (short)f2bf(f0.x); rows[1][i] = (short)f2bf(f0.y);
                rows[2][i] = (short)f2bf(f0.z); rows[3][i] = (short)f2bf(f0.w);
                rows[4][i] = (short)f2bf(f1.x); rows[5][i] = (short)f2bf(f1.y);
                rows[6][i] = (short)f2bf(f1.z); rows[7][i] = (short)f2bf(f1.w);
            }
            #pragma unroll
            for (int j = 0; j < 4; ++j) {
                *(bf16x8*)&xs[(tt * 4 + j) * 72 + cc * 8]       = rows[j];
                *(bf16x8*)&xs[(128 + tt * 4 + j) * 72 + cc * 8] = rows[4 + j];
            }
        }
        __syncthreads();
        #pragma unroll
        for (int kc = 0; kc < 2; ++kc) {
            int ko = kc * 32 + quad * 8;
            bf16x8 afr[4], bfr[4];
            #pragma unroll
            for (int mi = 0; mi < 4; ++mi)
                afr[mi] = *(const bf16x8*)&wa[(mi * 16 + m) * 72 + ko];
            #pragma unroll
            for (int ni = 0; ni < 4; ++ni)
                bfr[ni] = *(const bf16x8*)&xs[(wv * 64 + ni * 16 + m) * 72 + ko];
            #pragma unroll
            for (int mi = 0; mi < 4; ++mi)
                #pragma unroll
                for (int ni = 0; ni < 4; ++ni)
                    acc[mi][ni] = __builtin_amdgcn_mfma_f32_16x16x32_bf16(
                        afr[mi], bfr[ni], acc[mi][ni], 0, 0, 0);
        }
    }
    float* og = out + ((size_t)n * Cc * Vv + v) * Tt + t0 + wv * 64 + m;
    #pragma unroll
    for (int mi = 0; mi < 4; ++mi)
        #pragma unroll
        for (int r = 0; r < 4; ++r) {
            int c = mi * 16 + quad * 4 + r;
            float* orow = og + (size_t)c * Vv * Tt;
            #pragma unroll
            for (int ni = 0; ni < 4; ++ni)
                orow[ni * 16] = acc[mi][ni][r];
        }
}

extern "C" void kernel_launch(void* const* d_in, const int* in_sizes, int n_in,
                              void* d_out, int out_size, void* d_ws, size_t ws_size,
                              hipStream_t stream) {
    const float* x = (const float*)d_in[0];   // [32,64,25,1024]
    const float* W = (const float*)d_in[1];   // [25,192,64]
    const float* A = (const float*)d_in[2];   // [3,25,25]
    float* out = (float*)d_out;

    const size_t xb_elems   = (size_t)Nn * Vv * Tt * 64;       // 52,428,800
    const size_t weff_elems = (size_t)Vv * Vv * 4096;          //  2,560,000
    const size_t need = (xb_elems + weff_elems) * sizeof(unsigned short);

    if (ws_size >= need) {
        unsigned short* xb   = (unsigned short*)d_ws;
        unsigned short* Weff = xb + xb_elems;
        prep_fused<<<dim3(Vv * Vv + Nn * Vv * 8), dim3(256), 0, stream>>>(x, W, A, xb, Weff);
        gc_fast<<<dim3(3200), dim3(256), 0, stream>>>(xb, Weff, out);
    } else {
        unsigned short* Weff = (unsigned short*)d_ws;
        weff_prep_plain<<<dim3(Vv * Vv), dim3(256), 0, stream>>>(W, A, Weff);
        gc_plain<<<dim3(3200), dim3(256), 0, stream>>>(x, Weff, out);
    }
}